// Round 12
// baseline (190.010 us; speedup 1.0000x reference)
//
#include <hip/hip_runtime.h>
#include <math.h>

typedef _Float16 f16;
typedef _Float16 half4 __attribute__((ext_vector_type(4)));
typedef _Float16 half8 __attribute__((ext_vector_type(8)));
typedef float f32x4  __attribute__((ext_vector_type(4)));
typedef float f32x16 __attribute__((ext_vector_type(16)));

#define DEV __device__ __forceinline__

// ---------------- workspace layout (bytes) ----------------
#define W1F_OFF 0        // [L][nt2]      : 16 frags  = 16 KB   (x 2*log2e)
#define W2F_OFF 16384    // [L][kt4][nt2] : 64 frags  = 64 KB   (unscaled)
#define WOF_OFF 81920    // [L][u8][kt4]  : 256 frags = 256 KB  (x log2e)
#define B1T_OFF 344064   // [L][nt2][khi2][16] f32 b1 ROW-vec (x 2*log2e) = 2 KB
#define B2T_OFF 346112   // [L][nt2][khi2][16] f32 b2 ROW-vec (unscaled)  = 2 KB
#define SUMLOG_OFF 352256 // 1 fp32: sum over all layers/features of log|scale|
#define W0S_OFF 352320   // [L][16][16] f32 W0 x 2*log2e = 8 KB
#define B0S_OFF 360512   // [L][16]     f32 b0 x 2*log2e = 512 B
#define B1S_OFF 361088   // legacy (unused by flow)
#define BOT_OFF 363136   // [L][u8][khi2][16] f32 bout ROW-vec (x log2e, offset folded) = 8 KB

// ---------------- LDS: PER-WAVE ARENA (12800 B), 4 waves/block -------------
// H0/H only — the spline-param P region is GONE: Wout params now travel
// from MFMA output registers to the owning lane via khi-pair __shfl_xor
// (lane <-> lane^32), never touching LDS.
// H_STRIDE = 152 (38 dwords): b64 epilogue stores go 6l mod 32 -> 2
// lanes/bank group = free; odd rows are only 8B-aligned so H reads are
// b64 (half4) pairs — also conflict-free.
// Do NOT raise __launch_bounds__ waves/EU above 2: (256,4) r1/r2 and
// (256,3) r9 each made the allocator spill f32x16 blocks (60-500 MB).
// Occupancy is grid-limited anyway (B/64 = 2048 waves = 2/SIMD).
//   H0 : [64][48]  f16 h0 staging     @ arena+0     (3072)
//   H  : [64][152] f16 h1/h2 staging  @ arena+3072  (9728, ends 12800)
#define H0_OFF    0
#define H0_STRIDE 48
#define H_OFF     3072
#define H_STRIDE  152
#define ARENA     12800
#define LDS_BYTES (4 * ARENA)

DEV float frcp(float x){ return __builtin_amdgcn_rcpf(x); }

#if __has_builtin(__builtin_amdgcn_exp2f)
DEV float fexp2(float x){ return __builtin_amdgcn_exp2f(x); }
#else
DEV float fexp2(float x){ return exp2f(x); }
#endif
#if __has_builtin(__builtin_amdgcn_logf)
DEV float flog2(float x){ return __builtin_amdgcn_logf(x); }
#else
DEV float flog2(float x){ return log2f(x); }
#endif

#define LN2F    0.69314718056f
#define LOG2EF  1.4426950409f
#define TWOLOG2EF 2.8853900818f

// tanh with PRE-SCALED input: x' = 2*log2e * x_linear.
// tanh = 1 - 2/(2^{x'}+1). Robust without clamp. 4 instructions.
DEV float ftanh2(float x){
  float e = fexp2(x);
  float r = frcp(e + 1.f);
  return fmaf(-2.f, r, 1.f);
}

// Rational-quadratic spline forward + log-det (fp32, per-thread).
// p in LOG2 DOMAIN (params x log2e, softplus offset pre-folded at prep).
// ld_out in LOG2 units.
DEV void rq_spline(const float p[25], float xv, float &y_out, float &ld_out)
{
  float ew[8]; float sw = 0.f;
#pragma unroll
  for (int k = 0; k < 8; ++k){ ew[k] = fexp2(p[k]); sw += ew[k]; }
  float rw = frcp(sw) * 19.9992f;           // (RMAX-RMIN) - K*MIN_BIN

  float xpos[9];
  xpos[0] = -10.f;
#pragma unroll
  for (int k = 0; k < 8; ++k) xpos[k + 1] = xpos[k] + fmaf(ew[k], rw, 1e-4f);

  bool b[8];
  int idx = 0;
#pragma unroll
  for (int j = 1; j < 8; ++j){ b[j] = (xv >= xpos[j]); idx += b[j] ? 1 : 0; }

  float xk = xpos[0], ewk = ew[0];
#pragma unroll
  for (int j = 1; j < 8; ++j){
    xk  = b[j] ? xpos[j] : xk;
    ewk = b[j] ? ew[j]   : ewk;
  }
  float bw = fmaf(ewk, rw, 1e-4f);

  float eh[8]; float shs = 0.f;
#pragma unroll
  for (int k = 0; k < 8; ++k){ eh[k] = fexp2(p[8 + k]); shs += eh[k]; }
  float rh = frcp(shs) * 19.9992f;

  float S = 0.f, ehk = eh[0];
#pragma unroll
  for (int k = 1; k < 8; ++k){
    S   += b[k] ? eh[k - 1] : 0.f;
    ehk  = b[k] ? eh[k]     : ehk;
  }
  float yk = fmaf(S, rh, fmaf((float)idx, 1e-4f, -10.f));
  float bh = fmaf(ehk, rh, 1e-4f);

  float vA = p[16], vB = p[17];
#pragma unroll
  for (int j = 1; j < 8; ++j){
    vA = b[j] ? p[16 + j] : vA;
    vB = b[j] ? p[17 + j] : vB;
  }
  // softplus in log2 domain: ln(1+e^u) = ln2*(max(v,0)+log2(1+2^{-|v|}))
  float tA = fmaxf(vA, 0.f) + flog2(1.f + fexp2(-fabsf(vA)));
  float dk  = fmaf(LN2F, tA, 1e-4f);
  float tB = fmaxf(vB, 0.f) + flog2(1.f + fexp2(-fabsf(vB)));
  float dk1 = fmaf(LN2F, tB, 1e-4f);

  float rbw = frcp(bw);
  float s   = bh * rbw;
  float zf  = fminf(fmaxf((xv - xk) * rbw, 0.f), 1.f);
  float z1  = 1.f - zf;
  float zz  = zf * zf, z01 = zf * z1;
  float den = s + (dk1 + dk - 2.f * s) * z01;
  float rden = frcp(den);
  float yv  = yk + bh * (s * zz + dk * z01) * rden;
  float num = dk1 * zz + 2.f * s * z01 + dk * z1 * z1;
  float ldv2 = flog2(s * s * num * rden * rden);   // log2-domain

  bool outside = (xv <= -10.f) || (xv >= 10.f);
  y_out  = outside ? xv : yv;
  ld_out = outside ? 0.f : ldv2;
}

// ---------------- prep kernel: pack fp16 fragments into ws ----------------
// (unchanged from r11 — fragment formats identical)
extern "C" __global__ void __launch_bounds__(256)
prep_kernel(const float* __restrict__ W0, const float* __restrict__ b0,
            const float* __restrict__ W1, const float* __restrict__ b1,
            const float* __restrict__ W2, const float* __restrict__ b2,
            const float* __restrict__ Wo, const float* __restrict__ bout,
            const float* __restrict__ scale, char* __restrict__ ws)
{
  int tid = blockIdx.x * 256 + threadIdx.x;
  if (tid < 1024){                       // W1 frags: [L][nt2]  (x 2*log2e)
    int fi = tid >> 6, lane = tid & 63;
    int l = fi >> 1, nt = fi & 1;
    int n = nt * 32 + (lane & 31), khi = lane >> 5;
    half8 h;
#pragma unroll
    for (int j = 0; j < 8; ++j){ int k = khi * 8 + j; h[j] = (f16)(W1[l * 1024 + k * 64 + n] * TWOLOG2EF); }
    *(half8*)(ws + W1F_OFF + fi * 1024 + lane * 16) = h;
  } else if (tid < 5120){                // W2 frags: [L][kt4][nt2] (unscaled)
    int idx = tid - 1024;
    int fi = idx >> 6, lane = idx & 63;
    int l = fi >> 3, kt = (fi >> 1) & 3, nt = fi & 1;
    int n = nt * 32 + (lane & 31), khi = lane >> 5;
    half8 h;
#pragma unroll
    for (int j = 0; j < 8; ++j){ int k = kt * 16 + khi * 8 + j; h[j] = (f16)W2[l * 4096 + k * 64 + n]; }
    *(half8*)(ws + W2F_OFF + fi * 1024 + lane * 16) = h;
  } else if (tid < 21504){               // Wout used-col frags: [L][u8][kt4] (x log2e)
    int idx = tid - 5120;
    int fi = idx >> 6, lane = idx & 63;
    int l = fi >> 5, u = (fi >> 2) & 7, kt = fi & 3;
    int f = (l & 1) + 2 * u;
    int c = lane & 31, khi = lane >> 5;
    half8 h;
#pragma unroll
    for (int j = 0; j < 8; ++j){
      int k = kt * 16 + khi * 8 + j;
      float v = (c < 25) ? Wo[l * 25600 + k * 400 + f * 25 + c] * LOG2EF : 0.f;
      h[j] = (f16)v;
    }
    *(half8*)(ws + WOF_OFF + fi * 1024 + lane * 16) = h;
  } else if (tid < 22016){               // B1T row-bias: 512 floats (x 2*log2e)
    int idx = tid - 21504;               // = ((l*2+nt)*2+kh)*16 + i
    int l = idx >> 6, nt = (idx >> 5) & 1, kh = (idx >> 4) & 1, i = idx & 15;
    int r = (i & 3) + 8 * (i >> 2) + 4 * kh;
    ((float*)(ws + B1T_OFF))[idx] = b1[l * 64 + nt * 32 + r] * TWOLOG2EF;
  } else if (tid < 22528){               // B2T row-bias: 512 floats (unscaled)
    int idx = tid - 22016;
    int l = idx >> 6, nt = (idx >> 5) & 1, kh = (idx >> 4) & 1, i = idx & 15;
    int r = (i & 3) + 8 * (i >> 2) + 4 * kh;
    ((float*)(ws + B2T_OFF))[idx] = b2[l * 64 + nt * 32 + r];
  } else if (tid == 23552){              // sum of log|scale| over all layers
    float acc = 0.f;
    for (int i = 0; i < 128; ++i) acc += logf(fabsf(scale[i]));
    *(float*)(ws + SUMLOG_OFF) = acc;
  } else if (tid > 23552 && tid < 25601){ // W0 scaled copy: 2048 floats
    int idx = tid - 23553;
    ((float*)(ws + W0S_OFF))[idx] = W0[idx] * TWOLOG2EF;
  } else if (tid >= 25601 && tid < 25729){ // b0 scaled copy: 128 floats
    int idx = tid - 25601;
    ((float*)(ws + B0S_OFF))[idx] = b0[idx] * TWOLOG2EF;
  } else if (tid >= 26241 && tid < 28289){ // BOT row-bias: 2048 floats
    int idx = tid - 26241;               // = l*256 + u*32 + khi*16 + i
    int l = idx >> 8, u = (idx >> 5) & 7, kh = (idx >> 4) & 1, i = idx & 15;
    int f = (l & 1) + 2 * u;
    int r = (i & 3) + 8 * (i >> 2) + 4 * kh;
    float v = 0.f;
    if (r < 25){
      v = bout[l * 400 + f * 25 + r];
      if (r >= 16) v += 0.54116666f;     // softplus offset folded
      v *= LOG2EF;
    }
    ((float*)(ws + BOT_OFF))[idx] = v;
  }
}

// ---- load a 16-float row-bias vector (BOT layout) ----
DEV void load_botv(const char* __restrict__ ws, int l, int u, int khi,
                   float (&botv)[16])
{
  const f32x4* bp = (const f32x4*)(ws + BOT_OFF) + ((l * 8 + u) * 2 + khi) * 4;
  f32x4 q0 = bp[0], q1 = bp[1], q2 = bp[2], q3 = bp[3];
#pragma unroll
  for (int i = 0; i < 4; ++i){
    botv[i] = q0[i]; botv[4 + i] = q1[i]; botv[8 + i] = q2[i]; botv[12 + i] = q3[i];
  }
}

// ---- H b128-equivalent load split into two b64s (stride 152 rows are only
//      8B-aligned; ds b128 needs 16B). b64 at 38-dword stride is 2-way=free.
DEV half8 ld_h8_pair(const char* p)
{
  half4 lo = *(const half4*)(p);
  half4 hi = *(const half4*)(p + 8);
  half8 r;
#pragma unroll
  for (int i = 0; i < 4; ++i){ r[i] = lo[i]; r[4 + i] = hi[i]; }
  return r;
}

// ---- one Wout feature: SWAPPED MFMA (D^T = Wout^T . h2^T), REGISTER out --
// dp0/dp1 hold (row r(i,khi) = (i&3)+8*(i>>2)+4*khi, col ln31) of tiles
// mt=0/1: param r of samples ln31 / 32+ln31.
DEV void wout_mfma(const half8 (&a2)[2][4], const half8 (&bfn)[4],
                   const float (&botv)[16], f32x16 &dp0, f32x16 &dp1)
{
#pragma unroll
  for (int i = 0; i < 16; ++i){ dp0[i] = botv[i]; dp1[i] = botv[i]; }
#pragma unroll
  for (int kt = 0; kt < 4; ++kt){
    dp0 = __builtin_amdgcn_mfma_f32_32x32x16_f16(bfn[kt], a2[0][kt], dp0, 0, 0, 0);
    dp1 = __builtin_amdgcn_mfma_f32_32x32x16_f16(bfn[kt], a2[1][kt], dp1, 0, 0, 0);
  }
}

// ---- khi-pair register exchange: gather all 25 params of the lane's OWN
// sample from (dp0,dp1). Lane lambda's own sample sits in tile mt=khi; it
// already holds params r(i,khi); the other half (r(i,khi^1)) sits in lane
// lambda^32 at the SAME register index. One __shfl_xor(.,32) per index.
// (Replaces the entire P LDS round-trip: ~15 wide DS ops -> 13 exchanges.)
DEV void extract_p(const f32x16 &dp0, const f32x16 &dp1, int khi, float (&p)[25])
{
#pragma unroll
  for (int i = 0; i < 12; ++i){
    float send = khi ? dp0[i] : dp1[i];       // what the partner needs
    float recv = __shfl_xor(send, 32, 64);
    const int r0 = (i & 3) + 8 * (i >> 2);    // 0..3, 8..11, 16..19
    p[r0]     = khi ? recv   : dp0[i];        // param r0   of own sample
    p[r0 + 4] = khi ? dp1[i] : recv;          // param r0+4 of own sample
  }
  {
    float send = khi ? dp0[12] : dp1[12];
    float recv = __shfl_xor(send, 32, 64);
    p[24] = khi ? recv : dp0[12];             // r=24 (partner's r=28 unused)
  }
}

// ---------------- one coupling layer (arena = wave-private LDS) ------------
// 64 samples/wave, 1 lane/sample. All three GEMMs use the swapped MFMA
// (D^T = W^T . h^T). Wout params never touch LDS (register khi-exchange).
template<int PAR>
DEV void layer_mfma(int l,
                    const float* __restrict__ scv, const float* __restrict__ shv,
                    const char* __restrict__ ws, char* ldsw,
                    float (&z)[16], float &logdet,
                    int lane, int ln31, int khi)
{
  const float* w0  = (const float*)(ws + W0S_OFF) + l * 256;   // x 2*log2e
  const float* bb0 = (const float*)(ws + B0S_OFF) + l * 16;    // x 2*log2e

  // ---- hoisted weight-fragment loads (latency hidden behind h0 VALU) ----
  const half8* W1F = (const half8*)(ws + W1F_OFF);
  const half8* W2F = (const half8*)(ws + W2F_OFF);
  half8 w1f[2];
#pragma unroll
  for (int nt = 0; nt < 2; ++nt) w1f[nt] = W1F[(l * 2 + nt) * 64 + lane];
  half8 w2f[8];
#pragma unroll
  for (int kt = 0; kt < 4; ++kt)
#pragma unroll
    for (int nt = 0; nt < 2; ++nt)
      w2f[kt * 2 + nt] = W2F[((l * 4 + kt) * 2 + nt) * 64 + lane];

  // ---- h0 = tanh(mz @ W0 + b0), per-thread VALU (weights pre-scaled) ----
  float h0[16];
#pragma unroll
  for (int j = 0; j < 16; ++j) h0[j] = bb0[j];
#pragma unroll
  for (int u = 0; u < 8; ++u){
    const int f = (1 - PAR) + 2 * u;
    const float v = z[f];
#pragma unroll
    for (int j = 0; j < 16; ++j) h0[j] = fmaf(v, w0[f * 16 + j], h0[j]);
  }
  {
    half8 lo, hi;
#pragma unroll
    for (int j = 0; j < 8; ++j){ lo[j] = (f16)ftanh2(h0[j]); hi[j] = (f16)ftanh2(h0[8 + j]); }
    *(half8*)(ldsw + H0_OFF + lane * H0_STRIDE)      = lo;
    *(half8*)(ldsw + H0_OFF + lane * H0_STRIDE + 16) = hi;
  }

  // ---- W1 (swapped): D1^T[nt][mt] = W1^T . h0^T, bias row-vector init ----
  half8 a0[2];
#pragma unroll
  for (int mt = 0; mt < 2; ++mt)
    a0[mt] = *(const half8*)(ldsw + H0_OFF + (mt * 32 + ln31) * H0_STRIDE + khi * 16);
  f32x16 d1t[2][2];
  {
    const f32x4* B1T = (const f32x4*)(ws + B1T_OFF);
#pragma unroll
    for (int nt = 0; nt < 2; ++nt){
      const f32x4* bp = B1T + ((l * 2 + nt) * 2 + khi) * 4;
      f32x4 q0 = bp[0], q1 = bp[1], q2 = bp[2], q3 = bp[3];
#pragma unroll
      for (int mt = 0; mt < 2; ++mt)
#pragma unroll
        for (int i = 0; i < 4; ++i){
          d1t[nt][mt][i] = q0[i]; d1t[nt][mt][4 + i] = q1[i];
          d1t[nt][mt][8 + i] = q2[i]; d1t[nt][mt][12 + i] = q3[i];
        }
    }
  }
#pragma unroll
  for (int nt = 0; nt < 2; ++nt)
#pragma unroll
    for (int mt = 0; mt < 2; ++mt)
      d1t[nt][mt] = __builtin_amdgcn_mfma_f32_32x32x16_f16(w1f[nt], a0[mt], d1t[nt][mt], 0, 0, 0);
  // epilogue: tanh + pack 4 consecutive f16 -> b64 store (n = nt*32+8g+j+4khi)
#pragma unroll
  for (int nt = 0; nt < 2; ++nt)
#pragma unroll
    for (int mt = 0; mt < 2; ++mt){
      int s = mt * 32 + ln31;
#pragma unroll
      for (int g = 0; g < 4; ++g){
        half4 h4;
#pragma unroll
        for (int j = 0; j < 4; ++j) h4[j] = (f16)ftanh2(d1t[nt][mt][g * 4 + j]);
        *(half4*)(ldsw + H_OFF + s * H_STRIDE + nt * 64 + g * 16 + khi * 8) = h4;
      }
    }

  // ---- W2 (swapped): D2^T[nt][mt] = W2^T . h1^T ----
  half8 a1[2][4];
#pragma unroll
  for (int mt = 0; mt < 2; ++mt)
#pragma unroll
    for (int kt = 0; kt < 4; ++kt)
      a1[mt][kt] = ld_h8_pair(ldsw + H_OFF + (mt * 32 + ln31) * H_STRIDE + kt * 32 + khi * 16);
  f32x16 d2t[2][2];
  {
    const f32x4* B2T = (const f32x4*)(ws + B2T_OFF);
#pragma unroll
    for (int nt = 0; nt < 2; ++nt){
      const f32x4* bp = B2T + ((l * 2 + nt) * 2 + khi) * 4;
      f32x4 q0 = bp[0], q1 = bp[1], q2 = bp[2], q3 = bp[3];
#pragma unroll
      for (int mt = 0; mt < 2; ++mt)
#pragma unroll
        for (int i = 0; i < 4; ++i){
          d2t[nt][mt][i] = q0[i]; d2t[nt][mt][4 + i] = q1[i];
          d2t[nt][mt][8 + i] = q2[i]; d2t[nt][mt][12 + i] = q3[i];
        }
    }
  }
#pragma unroll
  for (int kt = 0; kt < 4; ++kt)
#pragma unroll
    for (int nt = 0; nt < 2; ++nt)
#pragma unroll
      for (int mt = 0; mt < 2; ++mt)
        d2t[nt][mt] = __builtin_amdgcn_mfma_f32_32x32x16_f16(w2f[kt * 2 + nt], a1[mt][kt], d2t[nt][mt], 0, 0, 0);

  // ---- prefetch feature u=0's Wout frags + row-bias (hidden behind epi) ----
  const half8* WOF = (const half8*)(ws + WOF_OFF);
  half8 bfn[4];
#pragma unroll
  for (int kt = 0; kt < 4; ++kt) bfn[kt] = WOF[((l * 8 + 0) * 4 + kt) * 64 + lane];
  float botv[16];
  load_botv(ws, l, 0, khi, botv);

  // epilogue: pack 4 consecutive f16 -> b64 store (no tanh)
#pragma unroll
  for (int nt = 0; nt < 2; ++nt)
#pragma unroll
    for (int mt = 0; mt < 2; ++mt){
      int s = mt * 32 + ln31;
#pragma unroll
      for (int g = 0; g < 4; ++g){
        half4 h4;
#pragma unroll
        for (int j = 0; j < 4; ++j) h4[j] = (f16)d2t[nt][mt][g * 4 + j];
        *(half4*)(ldsw + H_OFF + s * H_STRIDE + nt * 64 + g * 16 + khi * 8) = h4;
      }
    }

  // ---- h2 B-fragments (reused across all 8 features) ----
  half8 a2[2][4];
#pragma unroll
  for (int mt = 0; mt < 2; ++mt)
#pragma unroll
    for (int kt = 0; kt < 4; ++kt)
      a2[mt][kt] = ld_h8_pair(ldsw + H_OFF + (mt * 32 + ln31) * H_STRIDE + kt * 32 + khi * 16);

  // ---- feature-loop software pipeline, ALL-REGISTER ----
  // dp(u) extracted via khi-exchange at loop top; MFMA(u+1) issued into dp
  // BEFORE spline(u) so its issue+latency hide under the spline VALU chain.
  f32x16 dp0, dp1;
  wout_mfma(a2, bfn, botv, dp0, dp1);
#pragma unroll
  for (int kt = 0; kt < 4; ++kt) bfn[kt] = WOF[((l * 8 + 1) * 4 + kt) * 64 + lane];
  load_botv(ws, l, 1, khi, botv);

#pragma unroll 1
  for (int u = 0; u < 8; ++u){
    float p[25];
    extract_p(dp0, dp1, khi, p);

    // issue next feature's MFMA (WAR on dp orders after the exchange reads)
    if (u < 7){
      wout_mfma(a2, bfn, botv, dp0, dp1);
      if (u < 6){
#pragma unroll
        for (int kt = 0; kt < 4; ++kt) bfn[kt] = WOF[((l * 8 + u + 2) * 4 + kt) * 64 + lane];
        load_botv(ws, l, u + 2, khi, botv);
      }
    }

    const int f = PAR + 2 * u;
    float y, ld;
    rq_spline(p, z[f], y, ld);
    z[f] = y;
    logdet += ld;                       // log2-domain accumulation
  }

  // ---- affine (log|scale| sum precomputed in prep) ----
  const float* scp = scv + l * 16;
  const float* shp = shv + l * 16;
#pragma unroll
  for (int j = 0; j < 16; ++j)
    z[j] = fmaf(z[j], scp[j], shp[j]);
}

extern "C" __global__ void __launch_bounds__(256, 2)
flow_kernel(const float* __restrict__ x,
            const float* __restrict__ scv, const float* __restrict__ shv,
            const char* __restrict__ ws, float* __restrict__ out, int B)
{
  extern __shared__ char lds[];
  const int t    = threadIdx.x;
  const int lane = t & 63;
  const int wv   = t >> 6;
  const int ln31 = lane & 31;
  const int khi  = lane >> 5;
  char* ldsw = lds + wv * ARENA;        // wave-private arena
  const int g = blockIdx.x * 256 + t;

  float z[16];
  const float4* xv = reinterpret_cast<const float4*>(x + (size_t)g * 16);
  float4 a0 = xv[0], a1 = xv[1], a2 = xv[2], a3 = xv[3];
  z[0]=a0.x; z[1]=a0.y; z[2]=a0.z; z[3]=a0.w;
  z[4]=a1.x; z[5]=a1.y; z[6]=a1.z; z[7]=a1.w;
  z[8]=a2.x; z[9]=a2.y; z[10]=a2.z; z[11]=a2.w;
  z[12]=a3.x; z[13]=a3.y; z[14]=a3.z; z[15]=a3.w;

  float logdet = 0.f;                 // in log2 units
  for (int l = 7; l >= 0; --l){
    if (l & 1) layer_mfma<1>(l, scv, shv, ws, ldsw, z, logdet, lane, ln31, khi);
    else       layer_mfma<0>(l, scv, shv, ws, ldsw, z, logdet, lane, ln31, khi);
  }

  float sumlog = *(const float*)(ws + SUMLOG_OFF);
  float ss = 0.f;
#pragma unroll
  for (int j = 0; j < 16; ++j) ss = fmaf(z[j], z[j], ss);
  out[g] = fmaf(LN2F, logdet, -0.5f * ss - 14.7030165f + sumlog);
}

extern "C" void kernel_launch(void* const* d_in, const int* in_sizes, int n_in,
                              void* d_out, int out_size, void* d_ws, size_t ws_size,
                              hipStream_t stream)
{
  const float* x    = (const float*)d_in[0];
  const float* W0   = (const float*)d_in[1];
  const float* b0   = (const float*)d_in[2];
  const float* W1   = (const float*)d_in[3];
  const float* b1   = (const float*)d_in[4];
  const float* W2   = (const float*)d_in[5];
  const float* b2   = (const float*)d_in[6];
  const float* Wout = (const float*)d_in[7];
  const float* bout = (const float*)d_in[8];
  const float* scale= (const float*)d_in[9];
  const float* shift= (const float*)d_in[10];

  int B = in_sizes[0] / 16;

  hipLaunchKernelGGL(prep_kernel, dim3(111), dim3(256), 0, stream,
                     W0, b0, W1, b1, W2, b2, Wout, bout, scale, (char*)d_ws);

  hipLaunchKernelGGL(flow_kernel, dim3(B / 256), dim3(256), LDS_BYTES, stream,
                     x, scale, shift,
                     (const char*)d_ws, (float*)d_out, B);
}

// Round 13
// 177.510 us; speedup vs baseline: 1.0704x; 1.0704x over previous
//
#include <hip/hip_runtime.h>
#include <math.h>

typedef _Float16 f16;
typedef _Float16 half4 __attribute__((ext_vector_type(4)));
typedef _Float16 half8 __attribute__((ext_vector_type(8)));
typedef float f32x4  __attribute__((ext_vector_type(4)));
typedef float f32x16 __attribute__((ext_vector_type(16)));

#define DEV __device__ __forceinline__

// ---------------- workspace layout (bytes) ----------------
#define W1F_OFF 0        // [L][nt2]      : 16 frags  = 16 KB   (x 2*log2e)
#define W2F_OFF 16384    // [L][kt4][nt2] : 64 frags  = 64 KB   (unscaled)
#define WOF_OFF 81920    // [L][u8][kt4]  : 256 frags = 256 KB  (x log2e)
#define B1T_OFF 344064   // [L][nt2][khi2][16] f32 b1 ROW-vec (x 2*log2e) = 2 KB
#define B2T_OFF 346112   // [L][nt2][khi2][16] f32 b2 ROW-vec (unscaled)  = 2 KB
#define SUMLOG_OFF 352256 // 1 fp32: sum over all layers/features of log|scale|
#define W0F_OFF 352320   // [L][64] half8 A-frags of W0^T (mask-zeroed, x 2*log2e) = 8 KB
#define B0T_OFF 361088   // [L][khi2][16] f32 b0 ROW-vec (x 2*log2e) = 1 KB
#define BOT_OFF 363136   // [L][u8][khi2][16] f32 bout ROW-vec (x log2e, offset folded) = 8 KB

// ---------------- LDS: PER-WAVE ARENA (12800 B), 4 waves/block -------------
// All regions of a wave's arena lie in [wv*ARENA,(wv+1)*ARENA) — genuinely
// wave-private. Within one wave DS ops execute in program order, so P may
// alias H0+H: the a2 register reads (last H use) precede all P stores; the
// next layer's Z/H0 writes follow this layer's last P read (u=7).
// The H0 region triple-duties per layer (all per-wave program-order safe):
//   Z (z staged f16) -> z-frag loads -> h0 D^T stores -> a0 frag loads.
// Bank design: H_STRIDE=152 (38 dwords) keeps b64 epilogue stores 2-way
// (free); P f32x4 at stride 112 is 2-way (free, shows in counter but costs
// ~nothing per m136); h0 b64 stores at stride 48 are <=4-way (bounded).
// Do NOT raise __launch_bounds__ waves/EU above 2: (256,4) r1/r2 and
// (256,3) r9 each made the allocator spill f32x16 blocks (60-500 MB).
// Occupancy is grid-limited anyway (B/64 = 2048 waves = 2/SIMD).
//   H0 : [64][48]  f16 z/h0 staging   @ arena+0     (3072)
//   H  : [64][152] f16 h1/h2 staging  @ arena+3072  (9728, ends 12800)
//   P  : [64][112] f32 spline params  @ arena+0     (7168, aliases H0+H)
#define H0_OFF    0
#define H0_STRIDE 48
#define H_OFF     3072
#define H_STRIDE  152
#define P_OFF     0
#define P_STRIDE  112
#define ARENA     12800
#define LDS_BYTES (4 * ARENA)

DEV float frcp(float x){ return __builtin_amdgcn_rcpf(x); }

#if __has_builtin(__builtin_amdgcn_exp2f)
DEV float fexp2(float x){ return __builtin_amdgcn_exp2f(x); }
#else
DEV float fexp2(float x){ return exp2f(x); }
#endif
#if __has_builtin(__builtin_amdgcn_logf)
DEV float flog2(float x){ return __builtin_amdgcn_logf(x); }
#else
DEV float flog2(float x){ return log2f(x); }
#endif

#define LN2F    0.69314718056f
#define LOG2EF  1.4426950409f
#define TWOLOG2EF 2.8853900818f

// tanh with PRE-SCALED input: x' = 2*log2e * x_linear.
// tanh = 1 - 2/(2^{x'}+1). Robust without clamp. 4 instructions.
DEV float ftanh2(float x){
  float e = fexp2(x);
  float r = frcp(e + 1.f);
  return fmaf(-2.f, r, 1.f);
}

// Rational-quadratic spline forward + log-det (fp32, per-thread).
// p in LOG2 DOMAIN (params x log2e, softplus offset pre-folded at prep).
// ld_out in LOG2 units.
DEV void rq_spline(const float p[25], float xv, float &y_out, float &ld_out)
{
  float ew[8]; float sw = 0.f;
#pragma unroll
  for (int k = 0; k < 8; ++k){ ew[k] = fexp2(p[k]); sw += ew[k]; }
  float rw = frcp(sw) * 19.9992f;           // (RMAX-RMIN) - K*MIN_BIN

  float xpos[9];
  xpos[0] = -10.f;
#pragma unroll
  for (int k = 0; k < 8; ++k) xpos[k + 1] = xpos[k] + fmaf(ew[k], rw, 1e-4f);

  bool b[8];
  int idx = 0;
#pragma unroll
  for (int j = 1; j < 8; ++j){ b[j] = (xv >= xpos[j]); idx += b[j] ? 1 : 0; }

  float xk = xpos[0], ewk = ew[0];
#pragma unroll
  for (int j = 1; j < 8; ++j){
    xk  = b[j] ? xpos[j] : xk;
    ewk = b[j] ? ew[j]   : ewk;
  }
  float bw = fmaf(ewk, rw, 1e-4f);

  float eh[8]; float shs = 0.f;
#pragma unroll
  for (int k = 0; k < 8; ++k){ eh[k] = fexp2(p[8 + k]); shs += eh[k]; }
  float rh = frcp(shs) * 19.9992f;

  float S = 0.f, ehk = eh[0];
#pragma unroll
  for (int k = 1; k < 8; ++k){
    S   += b[k] ? eh[k - 1] : 0.f;
    ehk  = b[k] ? eh[k]     : ehk;
  }
  float yk = fmaf(S, rh, fmaf((float)idx, 1e-4f, -10.f));
  float bh = fmaf(ehk, rh, 1e-4f);

  float vA = p[16], vB = p[17];
#pragma unroll
  for (int j = 1; j < 8; ++j){
    vA = b[j] ? p[16 + j] : vA;
    vB = b[j] ? p[17 + j] : vB;
  }
  // softplus in log2 domain: ln(1+e^u) = ln2*(max(v,0)+log2(1+2^{-|v|}))
  float tA = fmaxf(vA, 0.f) + flog2(1.f + fexp2(-fabsf(vA)));
  float dk  = fmaf(LN2F, tA, 1e-4f);
  float tB = fmaxf(vB, 0.f) + flog2(1.f + fexp2(-fabsf(vB)));
  float dk1 = fmaf(LN2F, tB, 1e-4f);

  float rbw = frcp(bw);
  float s   = bh * rbw;
  float zf  = fminf(fmaxf((xv - xk) * rbw, 0.f), 1.f);
  float z1  = 1.f - zf;
  float zz  = zf * zf, z01 = zf * z1;
  float den = s + (dk1 + dk - 2.f * s) * z01;
  float rden = frcp(den);
  float yv  = yk + bh * (s * zz + dk * z01) * rden;
  float num = dk1 * zz + 2.f * s * z01 + dk * z1 * z1;
  float ldv2 = flog2(s * s * num * rden * rden);   // log2-domain

  bool outside = (xv <= -10.f) || (xv >= 10.f);
  y_out  = outside ? xv : yv;
  ld_out = outside ? 0.f : ldv2;
}

// ---------------- prep kernel: pack fp16 fragments into ws ----------------
// Scaling folded in: W0/b0/W1/b1 x 2*log2e (tanh exp2 path), Wout/bout
// x log2e (+ softplus offset into rows 16..24). W2/b2 UNscaled.
// W0F: A-fragment of W0^T with the coupling mask folded in (rows for dead
// input features zeroed — mask parity is fixed per layer).
// Row-bias vectors (B0T/B1T/B2T/BOT) follow the C/D map r=(i&3)+8*(i>>2)+4*khi.
extern "C" __global__ void __launch_bounds__(256)
prep_kernel(const float* __restrict__ W0, const float* __restrict__ b0,
            const float* __restrict__ W1, const float* __restrict__ b1,
            const float* __restrict__ W2, const float* __restrict__ b2,
            const float* __restrict__ Wo, const float* __restrict__ bout,
            const float* __restrict__ scale, char* __restrict__ ws)
{
  int tid = blockIdx.x * 256 + threadIdx.x;
  if (tid < 1024){                       // W1 frags: [L][nt2]  (x 2*log2e)
    int fi = tid >> 6, lane = tid & 63;
    int l = fi >> 1, nt = fi & 1;
    int n = nt * 32 + (lane & 31), khi = lane >> 5;
    half8 h;
#pragma unroll
    for (int j = 0; j < 8; ++j){ int k = khi * 8 + j; h[j] = (f16)(W1[l * 1024 + k * 64 + n] * TWOLOG2EF); }
    *(half8*)(ws + W1F_OFF + fi * 1024 + lane * 16) = h;
  } else if (tid < 5120){                // W2 frags: [L][kt4][nt2] (unscaled)
    int idx = tid - 1024;
    int fi = idx >> 6, lane = idx & 63;
    int l = fi >> 3, kt = (fi >> 1) & 3, nt = fi & 1;
    int n = nt * 32 + (lane & 31), khi = lane >> 5;
    half8 h;
#pragma unroll
    for (int j = 0; j < 8; ++j){ int k = kt * 16 + khi * 8 + j; h[j] = (f16)W2[l * 4096 + k * 64 + n]; }
    *(half8*)(ws + W2F_OFF + fi * 1024 + lane * 16) = h;
  } else if (tid < 21504){               // Wout used-col frags: [L][u8][kt4] (x log2e)
    int idx = tid - 5120;
    int fi = idx >> 6, lane = idx & 63;
    int l = fi >> 5, u = (fi >> 2) & 7, kt = fi & 3;
    int f = (l & 1) + 2 * u;
    int c = lane & 31, khi = lane >> 5;
    half8 h;
#pragma unroll
    for (int j = 0; j < 8; ++j){
      int k = kt * 16 + khi * 8 + j;
      float v = (c < 25) ? Wo[l * 25600 + k * 400 + f * 25 + c] * LOG2EF : 0.f;
      h[j] = (f16)v;
    }
    *(half8*)(ws + WOF_OFF + fi * 1024 + lane * 16) = h;
  } else if (tid < 22016){               // B1T row-bias: 512 floats (x 2*log2e)
    int idx = tid - 21504;               // = ((l*2+nt)*2+kh)*16 + i
    int l = idx >> 6, nt = (idx >> 5) & 1, kh = (idx >> 4) & 1, i = idx & 15;
    int r = (i & 3) + 8 * (i >> 2) + 4 * kh;
    ((float*)(ws + B1T_OFF))[idx] = b1[l * 64 + nt * 32 + r] * TWOLOG2EF;
  } else if (tid < 22528){               // B2T row-bias: 512 floats (unscaled)
    int idx = tid - 22016;
    int l = idx >> 6, nt = (idx >> 5) & 1, kh = (idx >> 4) & 1, i = idx & 15;
    int r = (i & 3) + 8 * (i >> 2) + 4 * kh;
    ((float*)(ws + B2T_OFF))[idx] = b2[l * 64 + nt * 32 + r];
  } else if (tid == 23552){              // sum of log|scale| over all layers
    float acc = 0.f;
    for (int i = 0; i < 128; ++i) acc += logf(fabsf(scale[i]));
    *(float*)(ws + SUMLOG_OFF) = acc;
  } else if (tid > 23552 && tid < 24065){ // W0F frags: [L], 512 threads
    // A-layout: row n = lane&31 (h0 dim, 0..15 live), k = (lane>>5)*8+j
    // (input feature). Dead features ((k+l)%2==0) zeroed; x 2*log2e.
    int idx = tid - 23553;               // = l*64 + lane
    int l = idx >> 6, lane = idx & 63;
    int n = lane & 31, kh5 = lane >> 5;
    half8 h;
#pragma unroll
    for (int j = 0; j < 8; ++j){
      int k = kh5 * 8 + j;
      float v = 0.f;
      if (n < 16 && (((k + l) & 1) == 1))
        v = W0[l * 256 + k * 16 + n] * TWOLOG2EF;
      h[j] = (f16)v;
    }
    *(half8*)(ws + W0F_OFF + idx * 16) = h;
  } else if (tid >= 24065 && tid < 24321){ // B0T row-bias: 256 floats
    int idx = tid - 24065;               // = (l*2+kh)*16 + i
    int l = idx >> 5, kh = (idx >> 4) & 1, i = idx & 15;
    int r = (i & 3) + 8 * (i >> 2) + 4 * kh;
    float v = (r < 16) ? b0[l * 16 + r] * TWOLOG2EF : 0.f;
    ((float*)(ws + B0T_OFF))[idx] = v;
  } else if (tid >= 26241 && tid < 28289){ // BOT row-bias: 2048 floats
    int idx = tid - 26241;               // = l*256 + u*32 + khi*16 + i
    int l = idx >> 8, u = (idx >> 5) & 7, kh = (idx >> 4) & 1, i = idx & 15;
    int f = (l & 1) + 2 * u;
    int r = (i & 3) + 8 * (i >> 2) + 4 * kh;
    float v = 0.f;
    if (r < 25){
      v = bout[l * 400 + f * 25 + r];
      if (r >= 16) v += 0.54116666f;     // softplus offset folded
      v *= LOG2EF;
    }
    ((float*)(ws + BOT_OFF))[idx] = v;
  }
}

// ---- load a 16-float row-bias vector (BOT layout) ----
DEV void load_botv(const char* __restrict__ ws, int l, int u, int khi,
                   float (&botv)[16])
{
  const f32x4* bp = (const f32x4*)(ws + BOT_OFF) + ((l * 8 + u) * 2 + khi) * 4;
  f32x4 q0 = bp[0], q1 = bp[1], q2 = bp[2], q3 = bp[3];
#pragma unroll
  for (int i = 0; i < 4; ++i){
    botv[i] = q0[i]; botv[4 + i] = q1[i]; botv[8 + i] = q2[i]; botv[12 + i] = q3[i];
  }
}

// ---- H b128-equivalent load split into two b64s (stride 152 rows are only
//      8B-aligned; ds b128 needs 16B). b64 at 38-dword stride is 2-way=free.
DEV half8 ld_h8_pair(const char* p)
{
  half4 lo = *(const half4*)(p);
  half4 hi = *(const half4*)(p + 8);
  half8 r;
#pragma unroll
  for (int i = 0; i < 4; ++i){ r[i] = lo[i]; r[4 + i] = hi[i]; }
  return r;
}

// ---- one Wout feature: SWAPPED MFMA (D^T = Wout^T . h2^T) + f32x4 P-store -
// Each lane stores its sample's params as 3 f32x4 (+1 scalar for khi=0):
// byte layout within the P row: params 0..24 at bytes 0..99.
DEV void wout_feature(const half8 (&a2)[2][4], const half8 (&bfn)[4],
                      const float (&botv)[16], char* ldsw, int ln31, int khi)
{
  f32x16 dp[2];
#pragma unroll
  for (int mt = 0; mt < 2; ++mt)
#pragma unroll
    for (int i = 0; i < 16; ++i) dp[mt][i] = botv[i];
#pragma unroll
  for (int kt = 0; kt < 4; ++kt)
#pragma unroll
    for (int mt = 0; mt < 2; ++mt)
      dp[mt] = __builtin_amdgcn_mfma_f32_32x32x16_f16(bfn[kt], a2[mt][kt], dp[mt], 0, 0, 0);
#pragma unroll
  for (int mt = 0; mt < 2; ++mt){
    int s = mt * 32 + ln31;                        // wave-local sample row
    char* base = ldsw + P_OFF + s * P_STRIDE + khi * 16;  // 16B-aligned
    f32x4 c0, c1, c2;
#pragma unroll
    for (int i = 0; i < 4; ++i){
      c0[i] = dp[mt][i];       // params r = 4*khi + 0..3
      c1[i] = dp[mt][4 + i];   // params r = 4*khi + 8..11
      c2[i] = dp[mt][8 + i];   // params r = 4*khi + 16..19
    }
    *(f32x4*)(base)      = c0;
    *(f32x4*)(base + 32) = c1;
    *(f32x4*)(base + 64) = c2;
    if (khi == 0)                                  // r = 24 (khi=1 -> 28, skip)
      *(float*)(base + 96) = dp[mt][12];
  }
}

// ---------------- one coupling layer (arena = wave-private LDS) ------------
// 64 samples/wave, 1 lane/sample. ALL FOUR GEMMs (W0,W1,W2,Wout) use the
// swapped MFMA (D^T = W^T . h^T); outputs land sample-major. The h0 GEMV
// is now a single K=16 MFMA per mt-tile with the coupling mask and
// 2*log2e scale folded into the prepped W0F fragments (was 128 fmaf/lane).
template<int PAR>
DEV void layer_mfma(int l,
                    const float* __restrict__ scv, const float* __restrict__ shv,
                    const char* __restrict__ ws, char* ldsw,
                    float (&z)[16], float &logdet,
                    int lane, int ln31, int khi)
{
  // ---- hoisted weight-fragment loads (latency hidden behind staging) ----
  const half8* W1F = (const half8*)(ws + W1F_OFF);
  const half8* W2F = (const half8*)(ws + W2F_OFF);
  half8 w0f = *(const half8*)(ws + W0F_OFF + (l * 64 + lane) * 16);
  half8 w1f[2];
#pragma unroll
  for (int nt = 0; nt < 2; ++nt) w1f[nt] = W1F[(l * 2 + nt) * 64 + lane];
  half8 w2f[8];
#pragma unroll
  for (int kt = 0; kt < 4; ++kt)
#pragma unroll
    for (int nt = 0; nt < 2; ++nt)
      w2f[kt * 2 + nt] = W2F[((l * 4 + kt) * 2 + nt) * 64 + lane];

  // ---- W0 (swapped, K=16): stage z as f16, D0^T = W0^T . z^T ----
  // Z/H0 region reuse is per-wave program-order safe: z-stores -> z-frag
  // loads -> h0 stores (overwrite Z) -> a0 frag loads.
  {
    half8 zlo, zhi;
#pragma unroll
    for (int j = 0; j < 8; ++j){ zlo[j] = (f16)z[j]; zhi[j] = (f16)z[8 + j]; }
    *(half8*)(ldsw + H0_OFF + lane * H0_STRIDE)      = zlo;
    *(half8*)(ldsw + H0_OFF + lane * H0_STRIDE + 16) = zhi;
  }
  f32x16 d0t[2];
  {
    const f32x4* bp = (const f32x4*)(ws + B0T_OFF) + (l * 2 + khi) * 4;
    f32x4 q0 = bp[0], q1 = bp[1], q2 = bp[2], q3 = bp[3];
#pragma unroll
    for (int mt = 0; mt < 2; ++mt)
#pragma unroll
      for (int i = 0; i < 4; ++i){
        d0t[mt][i] = q0[i]; d0t[mt][4 + i] = q1[i];
        d0t[mt][8 + i] = q2[i]; d0t[mt][12 + i] = q3[i];
      }
  }
  {
    half8 zf[2];
#pragma unroll
    for (int mt = 0; mt < 2; ++mt)
      zf[mt] = *(const half8*)(ldsw + H0_OFF + (mt * 32 + ln31) * H0_STRIDE + khi * 16);
#pragma unroll
    for (int mt = 0; mt < 2; ++mt)
      d0t[mt] = __builtin_amdgcn_mfma_f32_32x32x16_f16(w0f, zf[mt], d0t[mt], 0, 0, 0);
  }
  // epilogue: tanh + store meaningful rows (i<8 -> r = g*8 + 4*khi + j < 16)
#pragma unroll
  for (int mt = 0; mt < 2; ++mt){
    int s = mt * 32 + ln31;
#pragma unroll
    for (int g = 0; g < 2; ++g){
      half4 h4;
#pragma unroll
      for (int j = 0; j < 4; ++j) h4[j] = (f16)ftanh2(d0t[mt][g * 4 + j]);
      *(half4*)(ldsw + H0_OFF + s * H0_STRIDE + g * 16 + khi * 8) = h4;
    }
  }

  // ---- W1 (swapped): D1^T[nt][mt] = W1^T . h0^T, bias row-vector init ----
  half8 a0[2];
#pragma unroll
  for (int mt = 0; mt < 2; ++mt)
    a0[mt] = *(const half8*)(ldsw + H0_OFF + (mt * 32 + ln31) * H0_STRIDE + khi * 16);
  f32x16 d1t[2][2];
  {
    const f32x4* B1T = (const f32x4*)(ws + B1T_OFF);
#pragma unroll
    for (int nt = 0; nt < 2; ++nt){
      const f32x4* bp = B1T + ((l * 2 + nt) * 2 + khi) * 4;
      f32x4 q0 = bp[0], q1 = bp[1], q2 = bp[2], q3 = bp[3];
#pragma unroll
      for (int mt = 0; mt < 2; ++mt)
#pragma unroll
        for (int i = 0; i < 4; ++i){
          d1t[nt][mt][i] = q0[i]; d1t[nt][mt][4 + i] = q1[i];
          d1t[nt][mt][8 + i] = q2[i]; d1t[nt][mt][12 + i] = q3[i];
        }
    }
  }
#pragma unroll
  for (int nt = 0; nt < 2; ++nt)
#pragma unroll
    for (int mt = 0; mt < 2; ++mt)
      d1t[nt][mt] = __builtin_amdgcn_mfma_f32_32x32x16_f16(w1f[nt], a0[mt], d1t[nt][mt], 0, 0, 0);
  // epilogue: tanh + pack 4 consecutive f16 -> b64 store (n = nt*32+8g+j+4khi)
#pragma unroll
  for (int nt = 0; nt < 2; ++nt)
#pragma unroll
    for (int mt = 0; mt < 2; ++mt){
      int s = mt * 32 + ln31;
#pragma unroll
      for (int g = 0; g < 4; ++g){
        half4 h4;
#pragma unroll
        for (int j = 0; j < 4; ++j) h4[j] = (f16)ftanh2(d1t[nt][mt][g * 4 + j]);
        *(half4*)(ldsw + H_OFF + s * H_STRIDE + nt * 64 + g * 16 + khi * 8) = h4;
      }
    }

  // ---- W2 (swapped): D2^T[nt][mt] = W2^T . h1^T ----
  half8 a1[2][4];
#pragma unroll
  for (int mt = 0; mt < 2; ++mt)
#pragma unroll
    for (int kt = 0; kt < 4; ++kt)
      a1[mt][kt] = ld_h8_pair(ldsw + H_OFF + (mt * 32 + ln31) * H_STRIDE + kt * 32 + khi * 16);
  f32x16 d2t[2][2];
  {
    const f32x4* B2T = (const f32x4*)(ws + B2T_OFF);
#pragma unroll
    for (int nt = 0; nt < 2; ++nt){
      const f32x4* bp = B2T + ((l * 2 + nt) * 2 + khi) * 4;
      f32x4 q0 = bp[0], q1 = bp[1], q2 = bp[2], q3 = bp[3];
#pragma unroll
      for (int mt = 0; mt < 2; ++mt)
#pragma unroll
        for (int i = 0; i < 4; ++i){
          d2t[nt][mt][i] = q0[i]; d2t[nt][mt][4 + i] = q1[i];
          d2t[nt][mt][8 + i] = q2[i]; d2t[nt][mt][12 + i] = q3[i];
        }
    }
  }
#pragma unroll
  for (int kt = 0; kt < 4; ++kt)
#pragma unroll
    for (int nt = 0; nt < 2; ++nt)
#pragma unroll
      for (int mt = 0; mt < 2; ++mt)
        d2t[nt][mt] = __builtin_amdgcn_mfma_f32_32x32x16_f16(w2f[kt * 2 + nt], a1[mt][kt], d2t[nt][mt], 0, 0, 0);

  // ---- prefetch feature u=0's Wout frags + row-bias (hidden behind epi) ----
  const half8* WOF = (const half8*)(ws + WOF_OFF);
  half8 bfn[4];
#pragma unroll
  for (int kt = 0; kt < 4; ++kt) bfn[kt] = WOF[((l * 8 + 0) * 4 + kt) * 64 + lane];
  float botv[16];
  load_botv(ws, l, 0, khi, botv);

  // epilogue: pack 4 consecutive f16 -> b64 store (no tanh)
#pragma unroll
  for (int nt = 0; nt < 2; ++nt)
#pragma unroll
    for (int mt = 0; mt < 2; ++mt){
      int s = mt * 32 + ln31;
#pragma unroll
      for (int g = 0; g < 4; ++g){
        half4 h4;
#pragma unroll
        for (int j = 0; j < 4; ++j) h4[j] = (f16)d2t[nt][mt][g * 4 + j];
        *(half4*)(ldsw + H_OFF + s * H_STRIDE + nt * 64 + g * 16 + khi * 8) = h4;
      }
    }

  // ---- h2 B-fragments (reused across all 8 features). After these reads
  //      this wave's H0/H bytes are dead -> P (arena+0) may alias them. ----
  half8 a2[2][4];
#pragma unroll
  for (int mt = 0; mt < 2; ++mt)
#pragma unroll
    for (int kt = 0; kt < 4; ++kt)
      a2[mt][kt] = ld_h8_pair(ldsw + H_OFF + (mt * 32 + ln31) * H_STRIDE + kt * 32 + khi * 16);

  // ---- feature-loop software pipeline (r8 schedule, arena P) ----
  // p_{u+1} MFMA + store issued BEFORE spline(u); per-wave DS program order
  // makes the single P slot safe (reads of p_u precede stores of p_{u+1}).
  wout_feature(a2, bfn, botv, ldsw, ln31, khi);
#pragma unroll
  for (int kt = 0; kt < 4; ++kt) bfn[kt] = WOF[((l * 8 + 1) * 4 + kt) * 64 + lane];
  load_botv(ws, l, 1, khi, botv);

#pragma unroll 1
  for (int u = 0; u < 8; ++u){
    // read own sample's p for feature u: 6 x f32x4 + 1 scalar (16B-aligned)
    float p[25];
    {
      const char* pb = ldsw + P_OFF + lane * P_STRIDE;
#pragma unroll
      for (int q = 0; q < 6; ++q){
        f32x4 v = *(const f32x4*)(pb + q * 16);
#pragma unroll
        for (int i = 0; i < 4; ++i) p[q * 4 + i] = v[i];
      }
      p[24] = *(const float*)(pb + 96);
    }

    // issue next feature's MFMA + store before the spline
    if (u < 7){
      wout_feature(a2, bfn, botv, ldsw, ln31, khi);
      if (u < 6){
#pragma unroll
        for (int kt = 0; kt < 4; ++kt) bfn[kt] = WOF[((l * 8 + u + 2) * 4 + kt) * 64 + lane];
        load_botv(ws, l, u + 2, khi, botv);
      }
    }

    const int f = PAR + 2 * u;
    float y, ld;
    rq_spline(p, z[f], y, ld);
    z[f] = y;
    logdet += ld;                       // log2-domain accumulation
  }

  // ---- affine (log|scale| sum precomputed in prep) ----
  const float* scp = scv + l * 16;
  const float* shp = shv + l * 16;
#pragma unroll
  for (int j = 0; j < 16; ++j)
    z[j] = fmaf(z[j], scp[j], shp[j]);
}

extern "C" __global__ void __launch_bounds__(256, 2)
flow_kernel(const float* __restrict__ x,
            const float* __restrict__ scv, const float* __restrict__ shv,
            const char* __restrict__ ws, float* __restrict__ out, int B)
{
  extern __shared__ char lds[];
  const int t    = threadIdx.x;
  const int lane = t & 63;
  const int wv   = t >> 6;
  const int ln31 = lane & 31;
  const int khi  = lane >> 5;
  char* ldsw = lds + wv * ARENA;        // wave-private arena
  const int g = blockIdx.x * 256 + t;

  float z[16];
  const float4* xv = reinterpret_cast<const float4*>(x + (size_t)g * 16);
  float4 a0 = xv[0], a1 = xv[1], a2 = xv[2], a3 = xv[3];
  z[0]=a0.x; z[1]=a0.y; z[2]=a0.z; z[3]=a0.w;
  z[4]=a1.x; z[5]=a1.y; z[6]=a1.z; z[7]=a1.w;
  z[8]=a2.x; z[9]=a2.y; z[10]=a2.z; z[11]=a2.w;
  z[12]=a3.x; z[13]=a3.y; z[14]=a3.z; z[15]=a3.w;

  float logdet = 0.f;                 // in log2 units
  for (int l = 7; l >= 0; --l){
    if (l & 1) layer_mfma<1>(l, scv, shv, ws, ldsw, z, logdet, lane, ln31, khi);
    else       layer_mfma<0>(l, scv, shv, ws, ldsw, z, logdet, lane, ln31, khi);
  }

  float sumlog = *(const float*)(ws + SUMLOG_OFF);
  float ss = 0.f;
#pragma unroll
  for (int j = 0; j < 16; ++j) ss = fmaf(z[j], z[j], ss);
  out[g] = fmaf(LN2F, logdet, -0.5f * ss - 14.7030165f + sumlog);
}

extern "C" void kernel_launch(void* const* d_in, const int* in_sizes, int n_in,
                              void* d_out, int out_size, void* d_ws, size_t ws_size,
                              hipStream_t stream)
{
  const float* x    = (const float*)d_in[0];
  const float* W0   = (const float*)d_in[1];
  const float* b0   = (const float*)d_in[2];
  const float* W1   = (const float*)d_in[3];
  const float* b1   = (const float*)d_in[4];
  const float* W2   = (const float*)d_in[5];
  const float* b2   = (const float*)d_in[6];
  const float* Wout = (const float*)d_in[7];
  const float* bout = (const float*)d_in[8];
  const float* scale= (const float*)d_in[9];
  const float* shift= (const float*)d_in[10];

  int B = in_sizes[0] / 16;

  hipLaunchKernelGGL(prep_kernel, dim3(111), dim3(256), 0, stream,
                     W0, b0, W1, b1, W2, b2, Wout, bout, scale, (char*)d_ws);

  hipLaunchKernelGGL(flow_kernel, dim3(B / 256), dim3(256), LDS_BYTES, stream,
                     x, scale, shift,
                     (const char*)d_ws, (float*)d_out, B);
}